// Round 6
// baseline (2519.750 us; speedup 1.0000x reference)
//
#include <hip/hip_runtime.h>

// OnLSTMCell fused pipeline for MI355X (gfx950).
// B=8192, input=1024, hidden=1024, level=64, d_in=2048.
// ws layout (bytes), total ~117 MB:
//   A_HI   @ 0          : u16[8192*2048]  (32 MB)   bf16(concat(input,h_prev))
//   A_LO   @ 33554432   : u16[8192*2048]  (32 MB)   bf16 residual (level path precision)
//   W_HI   @ 67108864   : u16[4224*2048]  (16.5 MB) rows 0..4095 gate-interleaved (n=j*4+gate), 4096..4223 = W_level
//   WLEV_LO@ 84410368   : u16[128*2048]   (0.5 MB)
//   PART   @ 84934656   : f32[8][8192][128] (32 MB) split-K partials of level GEMM
//   IH     @ 118489088  : f32[8192*64]    (2 MB)
//   FH     @ 120586240  : f32[8192*64]    (2 MB)

typedef unsigned short u16;
typedef __attribute__((ext_vector_type(8))) short bf16x8;
typedef __attribute__((ext_vector_type(8))) short s8v;
typedef __attribute__((ext_vector_type(4))) float f32x4;
typedef __attribute__((ext_vector_type(4))) float v4f;

#define GLDS(g, l) __builtin_amdgcn_global_load_lds(                      \
    (const __attribute__((address_space(1))) void*)(g),                   \
    (__attribute__((address_space(3))) void*)(l), 16, 0, 0)

__device__ __forceinline__ u16 f2bf(float x) {
  unsigned u = __builtin_bit_cast(unsigned, x);
  u += 0x7FFFu + ((u >> 16) & 1u);
  return (u16)(u >> 16);
}
__device__ __forceinline__ float bf2f(u16 h) {
  unsigned u = ((unsigned)h) << 16;
  return __builtin_bit_cast(float, u);
}
__device__ __forceinline__ float fsig(float x) { return 1.0f / (1.0f + __expf(-x)); }
__device__ __forceinline__ float ftanhf(float x) { float e = __expf(2.0f * x); return 1.0f - 2.0f / (e + 1.0f); }

// ---------------------------------------------------------------- convert ---
__global__ __launch_bounds__(256) void k_convert(
    const float* __restrict__ inp, const float* __restrict__ hprev,
    const float* __restrict__ wl, const float* __restrict__ wlev,
    u16* __restrict__ Ahi, u16* __restrict__ Alo,
    u16* __restrict__ Whi, u16* __restrict__ Wlo)
{
  const int GA = (8192 * 2048) / 8;
  const int GW = (4224 * 2048) / 8;
  for (int gi = blockIdx.x * 256 + threadIdx.x; gi < GA + GW; gi += gridDim.x * 256) {
    if (gi < GA) {
      int e = gi << 3; int row = e >> 11, col = e & 2047;
      const float* src = (col < 1024) ? (inp + row * 1024 + col)
                                      : (hprev + row * 1024 + (col - 1024));
      v4f a = *(const v4f*)src, b = *(const v4f*)(src + 4);
      float vv[8] = {a.x, a.y, a.z, a.w, b.x, b.y, b.z, b.w};
      s8v hi, lo;
#pragma unroll
      for (int j = 0; j < 8; ++j) {
        u16 h = f2bf(vv[j]);
        hi[j] = (short)h;
        lo[j] = (short)f2bf(vv[j] - bf2f(h));
      }
      *(s8v*)(Ahi + e) = hi;
      *(s8v*)(Alo + e) = lo;
    } else {
      int e = (gi - GA) << 3; int n = e >> 11, k = e & 2047;
      const float* src;
      if (n < 4096) { int j = n >> 2, g = n & 3; src = wl + (size_t)((g << 10) | j) * 2048 + k; }
      else          { src = wlev + (size_t)(n - 4096) * 2048 + k; }
      v4f a = *(const v4f*)src, b = *(const v4f*)(src + 4);
      float vv[8] = {a.x, a.y, a.z, a.w, b.x, b.y, b.z, b.w};
      s8v hi, lo;
#pragma unroll
      for (int j = 0; j < 8; ++j) {
        u16 h = f2bf(vv[j]);
        hi[j] = (short)h;
        lo[j] = (short)f2bf(vv[j] - bf2f(h));
      }
      *(s8v*)(Whi + e) = hi;
      if (n >= 4096) *(s8v*)(Wlo + (size_t)(n - 4096) * 2048 + k) = lo;
    }
  }
}

// ----------------------------------------------- level GEMM (split-bf16) ---
__global__ __launch_bounds__(256) void k_gemm_level(
    const u16* __restrict__ Ahi, const u16* __restrict__ Alo,
    const u16* __restrict__ Whi, const u16* __restrict__ Wlo,
    float* __restrict__ part)
{
  __shared__ __align__(16) u16 smem[4 * 8192];
  u16 *Ah = smem, *Al = smem + 8192, *Bh = smem + 16384, *Bl = smem + 24576;
  const int tid = threadIdx.x, lane = tid & 63, wid = tid >> 6;
  const int wm = wid >> 1, wn = wid & 1;
  const int rm = blockIdx.x, s = blockIdx.y;
  const int lrow = lane >> 3, lcolE = (lane & 7) << 3;
  const int c16 = lane & 15, r16 = lane >> 4;
  f32x4 acc[4][4] = {};
  const u16* aBaseH = Ahi + (size_t)(rm << 7) * 2048;
  const u16* aBaseL = Alo + (size_t)(rm << 7) * 2048;
  const u16* bBaseH = Whi + (size_t)4096 * 2048;

  for (int kt = 0; kt < 4; ++kt) {
    const int k0 = (s << 8) + (kt << 6);
#pragma unroll
    for (int q = 0; q < 4; ++q) {
      const int ca = (wid << 2) + q;
      size_t roff = (size_t)((ca << 3) + lrow) * 2048 + k0 + lcolE;
      GLDS(aBaseH + roff, Ah + (ca << 9));
      GLDS(aBaseL + roff, Al + (ca << 9));
      GLDS(bBaseH + roff, Bh + (ca << 9));
      GLDS(Wlo + roff,    Bl + (ca << 9));
    }
    __syncthreads();
#pragma unroll
    for (int ks = 0; ks < 2; ++ks) {
      bf16x8 ah[4], al[4];
#pragma unroll
      for (int i = 0; i < 4; ++i) {
        int off = ((wm << 6) + (i << 4) + c16) * 64 + (ks << 5) + (r16 << 3);
        ah[i] = *(const bf16x8*)(Ah + off);
        al[i] = *(const bf16x8*)(Al + off);
      }
#pragma unroll
      for (int j = 0; j < 4; ++j) {
        int off = ((wn << 6) + (j << 4) + c16) * 64 + (ks << 5) + (r16 << 3);
        bf16x8 bh = *(const bf16x8*)(Bh + off);
        bf16x8 bl = *(const bf16x8*)(Bl + off);
#pragma unroll
        for (int i = 0; i < 4; ++i) {
          acc[i][j] = __builtin_amdgcn_mfma_f32_16x16x32_bf16(ah[i], bh, acc[i][j], 0, 0, 0);
          acc[i][j] = __builtin_amdgcn_mfma_f32_16x16x32_bf16(al[i], bh, acc[i][j], 0, 0, 0);
          acc[i][j] = __builtin_amdgcn_mfma_f32_16x16x32_bf16(ah[i], bl, acc[i][j], 0, 0, 0);
        }
      }
    }
    __syncthreads();
  }
#pragma unroll
  for (int mi = 0; mi < 4; ++mi)
#pragma unroll
    for (int ni = 0; ni < 4; ++ni)
#pragma unroll
      for (int r = 0; r < 4; ++r) {
        int ml = (wm << 6) + (mi << 4) + (r16 << 2) + r;
        int nl = (wn << 6) + (ni << 4) + c16;
        part[(size_t)((s << 13) + (rm << 7) + ml) * 128 + nl] = acc[mi][ni][r];
      }
}

// ------------------------------------------- softmax + cumsums (per row) ---
__global__ __launch_bounds__(256) void k_softmax(
    const float* __restrict__ part, float* __restrict__ ih, float* __restrict__ fh)
{
  const int tid = threadIdx.x, lane = tid & 63, w = tid >> 6;
  const int row = blockIdx.x * 4 + w;
  float vi = 0.f, vf = 0.f;
#pragma unroll
  for (int s = 0; s < 8; ++s) {
    vi += part[(size_t)((s << 13) + row) * 128 + lane];
    vf += part[(size_t)((s << 13) + row) * 128 + 64 + lane];
  }
  float mi = vi, mf = vf;
#pragma unroll
  for (int d = 1; d < 64; d <<= 1) {
    mi = fmaxf(mi, __shfl_xor(mi, d, 64));
    mf = fmaxf(mf, __shfl_xor(mf, d, 64));
  }
  float ei = __expf(vi - mi), ef = __expf(vf - mf);
  float si = ei, sf = ef;
#pragma unroll
  for (int d = 1; d < 64; d <<= 1) {
    si += __shfl_xor(si, d, 64);
    sf += __shfl_xor(sf, d, 64);
  }
  float pi = ei / si, pf = ef / sf;
  float ci = pi, cf = pf;
#pragma unroll
  for (int d = 1; d < 64; d <<= 1) {
    float t = __shfl_up(ci, d, 64); if (lane >= d) ci += t;
    float u = __shfl_up(cf, d, 64); if (lane >= d) cf += u;
  }
  ih[(row << 6) + lane] = 1.0f - (ci - pi);
  fh[(row << 6) + lane] = cf;
}

// -------------------------------------- main gates GEMM + fused epilogue ---
// 256x256 tile, 512 thr = 8 waves (2M x 4N), wave-tile 128x64 (acc 8x4 f32x4).
// BK=32, 64 K-tiles. LDS = 3 buffers x (A 256x32 + B 256x32) bf16 = 96 KB.
// Per K-tile t (buf t%3), 2 sub-phases:
//   ph1: 8 A-reads + 2 B-reads; stage A-granule of tile t+2 (2 GLDS);
//        barrier; lgkmcnt(0); setprio; 16 MFMA (N0,N1); barrier.
//   ph2: 2 B-reads; stage B-granule of tile t+2; barrier; lgkmcnt(0);
//        setprio; 16 MFMA (N2,N3); vmcnt(4); barrier.
// vmcnt ledger (induction): entering tile t, outstanding = tile t+1's 4
// loads exactly; during t issue t+2's 4 -> vmcnt(4) retires t+1 before the
// barrier preceding t+1's reads. Depth = 2 tiles in flight; never vmcnt(0)
// in-loop. WAR: t+2 overwrites buf (t+2)%3, last read at t-1 (lgkmcnt(0)
// before that tile's final barrier). Unroll-3 (compile-time bufs); t=63
// peeled (no stage); dummy stages at t=61,62 wrap (&63), drained after.
// Swizzle both-sides (rule 21): stage src k-slot ^= row&3; read slot
// r16 ^ (c16&3). XCD swizzle = r3's proven cm-fast (fetch 197 MB).
__global__ __launch_bounds__(512, 2) void k_gemm_main(
    const u16* __restrict__ Ab, const u16* __restrict__ Wb,
    const float* __restrict__ cprev, const float* __restrict__ ihp,
    const float* __restrict__ fhp, float* __restrict__ out)
{
  __shared__ __align__(16) u16 smem[49152];        // 96 KB; epi reuses 64 KB
  const int tid = threadIdx.x, lane = tid & 63, wid = tid >> 6;
  const int wm = wid >> 2, wn = wid & 3;           // 2 x 4 wave grid
  const int c16 = lane & 15, r16 = lane >> 4;

  // r3-proven XCD swizzle: 512 blocks = 8 XCD x 64; per XCD rm in 4 values
  // (4 MB A L2-resident), cm fast (W re-reads absorbed by L3).
  const int bx = blockIdx.x;
  const int nb = (bx & 7) * 64 + (bx >> 3);
  const int rm = nb >> 4, cm = nb & 15;            // 32 row x 16 col tiles

  // staging map: thread -> row sr (0..127 per load-half), 16B slot slq.
  const int sr = tid >> 2;
  const int slq = tid & 3;
  const int sx = (slq ^ (sr & 3)) << 3;            // inverse-swizzled k-offset
  const u16* pa = Ab + (size_t)(rm * 256 + sr) * 2048 + sx;
  const u16* pb = Wb + (size_t)(cm * 256 + sr) * 2048 + sx;
  char* const ldsT = (char*)smem + (wid << 10);    // + lane*16 by GLDS

  // ds_read bases (bytes): row stride 64 B, 4 swizzled 16 B k-slots.
  const int xa = (r16 ^ (c16 & 3)) << 4;
  const int abase = (wm * 128 + c16) * 64 + xa;            // + i*1024
  const int bbase = 16384 + (wn * 64 + c16) * 64 + xa;     // + j*1024

  f32x4 acc[8][4] = {};

#define STAGEG(tile, op, buf) do {                                     \
    const u16* s_ = ((op) ? pb : pa) + (size_t)(tile) * 32;            \
    char* d_ = ldsT + (buf) * 32768 + (op) * 16384;                    \
    GLDS(s_, d_);                                                      \
    GLDS(s_ + 128 * 2048, d_ + 8192);                                  \
  } while (0)

#define TILE(buf, t2, buf2, dostage) do {                              \
    bf16x8 aX[8], bS0, bS1, bS2, bS3;                                  \
    _Pragma("unroll")                                                  \
    for (int i = 0; i < 8; ++i)                                        \
      aX[i] = *(const bf16x8*)((const char*)smem + (buf) * 32768 + abase + i * 1024); \
    bS0 = *(const bf16x8*)((const char*)smem + (buf) * 32768 + bbase);         \
    bS1 = *(const bf16x8*)((const char*)smem + (buf) * 32768 + bbase + 1024);  \
    if (dostage) STAGEG((t2), 0, (buf2));                              \
    __builtin_amdgcn_s_barrier();                                      \
    asm volatile("s_waitcnt lgkmcnt(0)" ::: "memory");                 \
    __builtin_amdgcn_s_setprio(1);                                     \
    _Pragma("unroll")                                                  \
    for (int i = 0; i < 8; ++i) {                                      \
      acc[i][0] = __builtin_amdgcn_mfma_f32_16x16x32_bf16(aX[i], bS0, acc[i][0], 0, 0, 0); \
      acc[i][1] = __builtin_amdgcn_mfma_f32_16x16x32_bf16(aX[i], bS1, acc[i][1], 0, 0, 0); \
    }                                                                  \
    __builtin_amdgcn_s_setprio(0);                                     \
    __builtin_amdgcn_s_barrier();                                      \
    bS2 = *(const bf16x8*)((const char*)smem + (buf) * 32768 + bbase + 2048);  \
    bS3 = *(const bf16x8*)((const char*)smem + (buf) * 32768 + bbase + 3072);  \
    if (dostage) STAGEG((t2), 1, (buf2));                              \
    __builtin_amdgcn_s_barrier();                                      \
    asm volatile("s_waitcnt lgkmcnt(0)" ::: "memory");                 \
    __builtin_amdgcn_s_setprio(1);                                     \
    _Pragma("unroll")                                                  \
    for (int i = 0; i < 8; ++i) {                                      \
      acc[i][2] = __builtin_amdgcn_mfma_f32_16x16x32_bf16(aX[i], bS2, acc[i][2], 0, 0, 0); \
      acc[i][3] = __builtin_amdgcn_mfma_f32_16x16x32_bf16(aX[i], bS3, acc[i][3], 0, 0, 0); \
    }                                                                  \
    __builtin_amdgcn_s_setprio(0);                                     \
    if (dostage) asm volatile("s_waitcnt vmcnt(4)" ::: "memory");      \
    __builtin_amdgcn_s_barrier();                                      \
  } while (0)

  // prologue: tiles 0,1 -> bufs 0,1; vmcnt(4) forces tile 0 (tile 1 in flight).
  STAGEG(0, 0, 0); STAGEG(0, 1, 0);
  STAGEG(1, 0, 1); STAGEG(1, 1, 1);
  asm volatile("s_waitcnt vmcnt(4)" ::: "memory");
  __builtin_amdgcn_s_barrier();

  for (int u = 0; u < 21; ++u) {                   // tiles 0..62
    const int t0 = u * 3;
    TILE(0, (t0 + 2) & 63, 2, 1);
    TILE(1, (t0 + 3) & 63, 0, 1);
    TILE(2, (t0 + 4) & 63, 1, 1);
  }
  TILE(0, 0, 0, 0);                                // peeled tile 63 (buf 0)
#undef TILE
#undef STAGEG

  // drain dummy wrap stages before LDS reuse
  asm volatile("s_waitcnt vmcnt(0)" ::: "memory");
  __builtin_amdgcn_s_barrier();

  // ---- fused ON-LSTM epilogue: 4 row-passes, epi = f32[64][256] (64 KB) ----
  // Coalesced h/c stores: each wave writes 64 consecutive f32 = 256 B lines.
  float* epi = (float*)smem;
  for (int p = 0; p < 4; ++p) {
    if (wm == (p >> 1)) {
      const int i0 = (p & 1) * 4;
#pragma unroll
      for (int iq = 0; iq < 4; ++iq)
#pragma unroll
        for (int j = 0; j < 4; ++j)
#pragma unroll
          for (int r = 0; r < 4; ++r) {
            float v = acc[i0 + iq][j][r];
            v = ((c16 & 3) == 3) ? ftanhf(v) : fsig(v);
            epi[(iq * 16 + r16 * 4 + r) * 256 + wn * 64 + j * 16 + c16] = v;
          }
    }
    __syncthreads();
#pragma unroll
    for (int e = 0; e < 8; ++e) {
      int idx = (e << 9) + tid;
      int m = idx >> 6, jl = idx & 63;
      v4f v = *(const v4f*)(epi + m * 256 + (jl << 2));  // i,f,o,g (activated)
      int rowg = rm * 256 + p * 64 + m;
      int jg = cm * 64 + jl;                             // hidden index
      float cp = cprev[rowg * 1024 + jg];
      int lv = jg >> 4;
      float vih = ihp[(rowg << 6) + lv], vfh = fhp[(rowg << 6) + lv];
      float iv = v.x, fv = v.y, ov = v.z, gv = v.w;
      float wq = vih * vfh;
      float c = wq * (fv * cp + iv * gv) + (vfh - wq) * cp + (vih - wq) * gv;
      float h = ov * ftanhf(c);
      out[rowg * 1024 + jg] = h;
      out[8388608 + rowg * 1024 + jg] = c;
    }
    __syncthreads();
  }
}

// -------------------------------------------------------------- launcher ---
extern "C" void kernel_launch(void* const* d_in, const int* in_sizes, int n_in,
                              void* d_out, int out_size, void* d_ws, size_t ws_size,
                              hipStream_t stream) {
  (void)in_sizes; (void)n_in; (void)out_size; (void)ws_size;
  const float* inp   = (const float*)d_in[0];
  const float* hprev = (const float*)d_in[1];
  const float* cprev = (const float*)d_in[2];
  const float* wl    = (const float*)d_in[3];
  const float* wlev  = (const float*)d_in[4];
  float* out = (float*)d_out;
  char* ws = (char*)d_ws;

  u16* Ahi  = (u16*)(ws);
  u16* Alo  = (u16*)(ws + 33554432);
  u16* Whi  = (u16*)(ws + 67108864);
  u16* Wlo  = (u16*)(ws + 84410368);
  float* part = (float*)(ws + 84934656);
  float* ih   = (float*)(ws + 118489088);
  float* fh   = (float*)(ws + 120586240);

  k_convert<<<dim3(2048), dim3(256), 0, stream>>>(inp, hprev, wl, wlev, Ahi, Alo, Whi, Wlo);
  k_gemm_level<<<dim3(64, 8), dim3(256), 0, stream>>>(Ahi, Alo, Whi, Wlo, part);
  k_softmax<<<dim3(2048), dim3(256), 0, stream>>>(part, ih, fh);
  k_gemm_main<<<dim3(512), dim3(512), 0, stream>>>(Ahi, Whi, cprev, ih, fh, out);
}

// Round 7
// 243.986 us; speedup vs baseline: 10.3274x; 10.3274x over previous
//
#include <hip/hip_runtime.h>

// OnLSTMCell fused pipeline for MI355X (gfx950).
// B=8192, input=1024, hidden=1024, level=64, d_in=2048.
// ws layout (bytes), total ~117 MB:
//   A_HI   @ 0          : u16[8192*2048]  (32 MB)   bf16(concat(input,h_prev))
//   A_LO   @ 33554432   : u16[8192*2048]  (32 MB)   bf16 residual (level path precision)
//   W_HI   @ 67108864   : u16[4224*2048]  (16.5 MB) rows 0..4095 gate-interleaved (n=j*4+gate), 4096..4223 = W_level
//   WLEV_LO@ 84410368   : u16[128*2048]   (0.5 MB)
//   PART   @ 84934656   : f32[8][8192][128] (32 MB) split-K partials of level GEMM
//   IH     @ 118489088  : f32[8192*64]    (2 MB)
//   FH     @ 120586240  : f32[8192*64]    (2 MB)

typedef unsigned short u16;
typedef __attribute__((ext_vector_type(8))) short bf16x8;
typedef __attribute__((ext_vector_type(8))) short s8v;
typedef __attribute__((ext_vector_type(4))) float f32x4;
typedef __attribute__((ext_vector_type(4))) float v4f;

#define GLDS(g, l) __builtin_amdgcn_global_load_lds(                      \
    (const __attribute__((address_space(1))) void*)(g),                   \
    (__attribute__((address_space(3))) void*)(l), 16, 0, 0)

__device__ __forceinline__ u16 f2bf(float x) {
  unsigned u = __builtin_bit_cast(unsigned, x);
  u += 0x7FFFu + ((u >> 16) & 1u);
  return (u16)(u >> 16);
}
__device__ __forceinline__ float bf2f(u16 h) {
  unsigned u = ((unsigned)h) << 16;
  return __builtin_bit_cast(float, u);
}
__device__ __forceinline__ float fsig(float x) { return 1.0f / (1.0f + __expf(-x)); }
__device__ __forceinline__ float ftanhf(float x) { float e = __expf(2.0f * x); return 1.0f - 2.0f / (e + 1.0f); }

// ---------------------------------------------------------------- convert ---
__global__ __launch_bounds__(256) void k_convert(
    const float* __restrict__ inp, const float* __restrict__ hprev,
    const float* __restrict__ wl, const float* __restrict__ wlev,
    u16* __restrict__ Ahi, u16* __restrict__ Alo,
    u16* __restrict__ Whi, u16* __restrict__ Wlo)
{
  const int GA = (8192 * 2048) / 8;
  const int GW = (4224 * 2048) / 8;
  for (int gi = blockIdx.x * 256 + threadIdx.x; gi < GA + GW; gi += gridDim.x * 256) {
    if (gi < GA) {
      int e = gi << 3; int row = e >> 11, col = e & 2047;
      const float* src = (col < 1024) ? (inp + row * 1024 + col)
                                      : (hprev + row * 1024 + (col - 1024));
      v4f a = *(const v4f*)src, b = *(const v4f*)(src + 4);
      float vv[8] = {a.x, a.y, a.z, a.w, b.x, b.y, b.z, b.w};
      s8v hi, lo;
#pragma unroll
      for (int j = 0; j < 8; ++j) {
        u16 h = f2bf(vv[j]);
        hi[j] = (short)h;
        lo[j] = (short)f2bf(vv[j] - bf2f(h));
      }
      *(s8v*)(Ahi + e) = hi;
      *(s8v*)(Alo + e) = lo;
    } else {
      int e = (gi - GA) << 3; int n = e >> 11, k = e & 2047;
      const float* src;
      if (n < 4096) { int j = n >> 2, g = n & 3; src = wl + (size_t)((g << 10) | j) * 2048 + k; }
      else          { src = wlev + (size_t)(n - 4096) * 2048 + k; }
      v4f a = *(const v4f*)src, b = *(const v4f*)(src + 4);
      float vv[8] = {a.x, a.y, a.z, a.w, b.x, b.y, b.z, b.w};
      s8v hi, lo;
#pragma unroll
      for (int j = 0; j < 8; ++j) {
        u16 h = f2bf(vv[j]);
        hi[j] = (short)h;
        lo[j] = (short)f2bf(vv[j] - bf2f(h));
      }
      *(s8v*)(Whi + e) = hi;
      if (n >= 4096) *(s8v*)(Wlo + (size_t)(n - 4096) * 2048 + k) = lo;
    }
  }
}

// ----------------------------------------------- level GEMM (split-bf16) ---
__global__ __launch_bounds__(256) void k_gemm_level(
    const u16* __restrict__ Ahi, const u16* __restrict__ Alo,
    const u16* __restrict__ Whi, const u16* __restrict__ Wlo,
    float* __restrict__ part)
{
  __shared__ __align__(16) u16 smem[4 * 8192];
  u16 *Ah = smem, *Al = smem + 8192, *Bh = smem + 16384, *Bl = smem + 24576;
  const int tid = threadIdx.x, lane = tid & 63, wid = tid >> 6;
  const int wm = wid >> 1, wn = wid & 1;
  const int rm = blockIdx.x, s = blockIdx.y;
  const int lrow = lane >> 3, lcolE = (lane & 7) << 3;
  const int c16 = lane & 15, r16 = lane >> 4;
  f32x4 acc[4][4] = {};
  const u16* aBaseH = Ahi + (size_t)(rm << 7) * 2048;
  const u16* aBaseL = Alo + (size_t)(rm << 7) * 2048;
  const u16* bBaseH = Whi + (size_t)4096 * 2048;

  for (int kt = 0; kt < 4; ++kt) {
    const int k0 = (s << 8) + (kt << 6);
#pragma unroll
    for (int q = 0; q < 4; ++q) {
      const int ca = (wid << 2) + q;
      size_t roff = (size_t)((ca << 3) + lrow) * 2048 + k0 + lcolE;
      GLDS(aBaseH + roff, Ah + (ca << 9));
      GLDS(aBaseL + roff, Al + (ca << 9));
      GLDS(bBaseH + roff, Bh + (ca << 9));
      GLDS(Wlo + roff,    Bl + (ca << 9));
    }
    __syncthreads();
#pragma unroll
    for (int ks = 0; ks < 2; ++ks) {
      bf16x8 ah[4], al[4];
#pragma unroll
      for (int i = 0; i < 4; ++i) {
        int off = ((wm << 6) + (i << 4) + c16) * 64 + (ks << 5) + (r16 << 3);
        ah[i] = *(const bf16x8*)(Ah + off);
        al[i] = *(const bf16x8*)(Al + off);
      }
#pragma unroll
      for (int j = 0; j < 4; ++j) {
        int off = ((wn << 6) + (j << 4) + c16) * 64 + (ks << 5) + (r16 << 3);
        bf16x8 bh = *(const bf16x8*)(Bh + off);
        bf16x8 bl = *(const bf16x8*)(Bl + off);
#pragma unroll
        for (int i = 0; i < 4; ++i) {
          acc[i][j] = __builtin_amdgcn_mfma_f32_16x16x32_bf16(ah[i], bh, acc[i][j], 0, 0, 0);
          acc[i][j] = __builtin_amdgcn_mfma_f32_16x16x32_bf16(al[i], bh, acc[i][j], 0, 0, 0);
          acc[i][j] = __builtin_amdgcn_mfma_f32_16x16x32_bf16(ah[i], bl, acc[i][j], 0, 0, 0);
        }
      }
    }
    __syncthreads();
  }
#pragma unroll
  for (int mi = 0; mi < 4; ++mi)
#pragma unroll
    for (int ni = 0; ni < 4; ++ni)
#pragma unroll
      for (int r = 0; r < 4; ++r) {
        int ml = (wm << 6) + (mi << 4) + (r16 << 2) + r;
        int nl = (wn << 6) + (ni << 4) + c16;
        part[(size_t)((s << 13) + (rm << 7) + ml) * 128 + nl] = acc[mi][ni][r];
      }
}

// ------------------------------------------- softmax + cumsums (per row) ---
__global__ __launch_bounds__(256) void k_softmax(
    const float* __restrict__ part, float* __restrict__ ih, float* __restrict__ fh)
{
  const int tid = threadIdx.x, lane = tid & 63, w = tid >> 6;
  const int row = blockIdx.x * 4 + w;
  float vi = 0.f, vf = 0.f;
#pragma unroll
  for (int s = 0; s < 8; ++s) {
    vi += part[(size_t)((s << 13) + row) * 128 + lane];
    vf += part[(size_t)((s << 13) + row) * 128 + 64 + lane];
  }
  float mi = vi, mf = vf;
#pragma unroll
  for (int d = 1; d < 64; d <<= 1) {
    mi = fmaxf(mi, __shfl_xor(mi, d, 64));
    mf = fmaxf(mf, __shfl_xor(mf, d, 64));
  }
  float ei = __expf(vi - mi), ef = __expf(vf - mf);
  float si = ei, sf = ef;
#pragma unroll
  for (int d = 1; d < 64; d <<= 1) {
    si += __shfl_xor(si, d, 64);
    sf += __shfl_xor(sf, d, 64);
  }
  float pi = ei / si, pf = ef / sf;
  float ci = pi, cf = pf;
#pragma unroll
  for (int d = 1; d < 64; d <<= 1) {
    float t = __shfl_up(ci, d, 64); if (lane >= d) ci += t;
    float u = __shfl_up(cf, d, 64); if (lane >= d) cf += u;
  }
  ih[(row << 6) + lane] = 1.0f - (ci - pi);
  fh[(row << 6) + lane] = cf;
}

// -------------------------------------- main gates GEMM + fused epilogue ---
// 256x256 tile, 512 thr = 8 waves (2M x 4N), wave-tile 128x64 (acc 8x4 f32x4).
// BK=32, 64 K-tiles. LDS = 3 buffers x (A 256x32 + B 256x32) bf16 = 96 KB.
// Per K-tile t (buf t%3), 2 sub-phases (fine interleave, counted vmcnt(4),
// never 0 in-loop; ledger in r6 comment history — unchanged).
// RULE #20 FIX vs r6: epilogue passes are macro-expanded with LITERAL p so
// every acc[] subscript is compile-time (r6's runtime i0=(p&1)*4 demoted
// acc[8][4] to scratch -> 12.7 GB HBM round-trip, VGPR 88, 2.5 ms).
__global__ __launch_bounds__(512, 2) void k_gemm_main(
    const u16* __restrict__ Ab, const u16* __restrict__ Wb,
    const float* __restrict__ cprev, const float* __restrict__ ihp,
    const float* __restrict__ fhp, float* __restrict__ out)
{
  __shared__ __align__(16) u16 smem[49152];        // 96 KB; epi reuses 64 KB
  const int tid = threadIdx.x, lane = tid & 63, wid = tid >> 6;
  const int wm = wid >> 2, wn = wid & 3;           // 2 x 4 wave grid
  const int c16 = lane & 15, r16 = lane >> 4;

  // r3-proven XCD swizzle: 512 blocks = 8 XCD x 64; per XCD rm in 4 values
  // (4 MB A L2-resident), cm fast (W re-reads absorbed by L3).
  const int bx = blockIdx.x;
  const int nb = (bx & 7) * 64 + (bx >> 3);
  const int rm = nb >> 4, cm = nb & 15;            // 32 row x 16 col tiles

  // staging map: thread -> row sr (0..127 per load-half), 16B slot slq.
  const int sr = tid >> 2;
  const int slq = tid & 3;
  const int sx = (slq ^ (sr & 3)) << 3;            // inverse-swizzled k-offset
  const u16* pa = Ab + (size_t)(rm * 256 + sr) * 2048 + sx;
  const u16* pb = Wb + (size_t)(cm * 256 + sr) * 2048 + sx;
  char* const ldsT = (char*)smem + (wid << 10);    // + lane*16 by GLDS

  // ds_read bases (bytes): row stride 64 B, 4 swizzled 16 B k-slots.
  const int xa = (r16 ^ (c16 & 3)) << 4;
  const int abase = (wm * 128 + c16) * 64 + xa;            // + i*1024
  const int bbase = 16384 + (wn * 64 + c16) * 64 + xa;     // + j*1024

  f32x4 acc[8][4] = {};

#define STAGEG(tile, op, buf) do {                                     \
    const u16* s_ = ((op) ? pb : pa) + (size_t)(tile) * 32;            \
    char* d_ = ldsT + (buf) * 32768 + (op) * 16384;                    \
    GLDS(s_, d_);                                                      \
    GLDS(s_ + 128 * 2048, d_ + 8192);                                  \
  } while (0)

#define TILE(buf, t2, buf2, dostage) do {                              \
    bf16x8 aX[8], bS0, bS1, bS2, bS3;                                  \
    _Pragma("unroll")                                                  \
    for (int i = 0; i < 8; ++i)                                        \
      aX[i] = *(const bf16x8*)((const char*)smem + (buf) * 32768 + abase + i * 1024); \
    bS0 = *(const bf16x8*)((const char*)smem + (buf) * 32768 + bbase);         \
    bS1 = *(const bf16x8*)((const char*)smem + (buf) * 32768 + bbase + 1024);  \
    if (dostage) STAGEG((t2), 0, (buf2));                              \
    __builtin_amdgcn_s_barrier();                                      \
    asm volatile("s_waitcnt lgkmcnt(0)" ::: "memory");                 \
    __builtin_amdgcn_s_setprio(1);                                     \
    _Pragma("unroll")                                                  \
    for (int i = 0; i < 8; ++i) {                                      \
      acc[i][0] = __builtin_amdgcn_mfma_f32_16x16x32_bf16(aX[i], bS0, acc[i][0], 0, 0, 0); \
      acc[i][1] = __builtin_amdgcn_mfma_f32_16x16x32_bf16(aX[i], bS1, acc[i][1], 0, 0, 0); \
    }                                                                  \
    __builtin_amdgcn_s_setprio(0);                                     \
    __builtin_amdgcn_s_barrier();                                      \
    bS2 = *(const bf16x8*)((const char*)smem + (buf) * 32768 + bbase + 2048);  \
    bS3 = *(const bf16x8*)((const char*)smem + (buf) * 32768 + bbase + 3072);  \
    if (dostage) STAGEG((t2), 1, (buf2));                              \
    __builtin_amdgcn_s_barrier();                                      \
    asm volatile("s_waitcnt lgkmcnt(0)" ::: "memory");                 \
    __builtin_amdgcn_s_setprio(1);                                     \
    _Pragma("unroll")                                                  \
    for (int i = 0; i < 8; ++i) {                                      \
      acc[i][2] = __builtin_amdgcn_mfma_f32_16x16x32_bf16(aX[i], bS2, acc[i][2], 0, 0, 0); \
      acc[i][3] = __builtin_amdgcn_mfma_f32_16x16x32_bf16(aX[i], bS3, acc[i][3], 0, 0, 0); \
    }                                                                  \
    __builtin_amdgcn_s_setprio(0);                                     \
    if (dostage) asm volatile("s_waitcnt vmcnt(4)" ::: "memory");      \
    __builtin_amdgcn_s_barrier();                                      \
  } while (0)

  // prologue: tiles 0,1 -> bufs 0,1; vmcnt(4) forces tile 0 (tile 1 in flight).
  STAGEG(0, 0, 0); STAGEG(0, 1, 0);
  STAGEG(1, 0, 1); STAGEG(1, 1, 1);
  asm volatile("s_waitcnt vmcnt(4)" ::: "memory");
  __builtin_amdgcn_s_barrier();

  for (int u = 0; u < 21; ++u) {                   // tiles 0..62
    const int t0 = u * 3;
    TILE(0, (t0 + 2) & 63, 2, 1);
    TILE(1, (t0 + 3) & 63, 0, 1);
    TILE(2, (t0 + 4) & 63, 1, 1);
  }
  TILE(0, 0, 0, 0);                                // peeled tile 63 (buf 0)
#undef TILE
#undef STAGEG

  // drain dummy wrap stages before LDS reuse
  asm volatile("s_waitcnt vmcnt(0)" ::: "memory");
  __builtin_amdgcn_s_barrier();

  // ---- fused ON-LSTM epilogue: 4 row-passes, epi = f32[64][256] (64 KB) ----
  // LITERAL pass index (rule #20): all acc[] subscripts compile-time.
  float* epi = (float*)smem;
#define EPIPASS(p) do {                                                \
    if (wm == ((p) >> 1)) {                                            \
      _Pragma("unroll")                                                \
      for (int iq = 0; iq < 4; ++iq)                                   \
        _Pragma("unroll")                                              \
        for (int j = 0; j < 4; ++j)                                    \
          _Pragma("unroll")                                            \
          for (int r = 0; r < 4; ++r) {                                \
            float v = acc[((p) & 1) * 4 + iq][j][r];                   \
            v = ((c16 & 3) == 3) ? ftanhf(v) : fsig(v);                \
            epi[(iq * 16 + r16 * 4 + r) * 256 + wn * 64 + j * 16 + c16] = v; \
          }                                                            \
    }                                                                  \
    __syncthreads();                                                   \
    _Pragma("unroll")                                                  \
    for (int e = 0; e < 8; ++e) {                                      \
      int idx = (e << 9) + tid;                                        \
      int m = idx >> 6, jl = idx & 63;                                 \
      v4f v = *(const v4f*)(epi + m * 256 + (jl << 2));                \
      int rowg = rm * 256 + (p) * 64 + m;                              \
      int jg = cm * 64 + jl;                                           \
      float cp = cprev[rowg * 1024 + jg];                              \
      int lv = jg >> 4;                                                \
      float vih = ihp[(rowg << 6) + lv], vfh = fhp[(rowg << 6) + lv];  \
      float iv = v.x, fv = v.y, ov = v.z, gv = v.w;                    \
      float wq = vih * vfh;                                            \
      float c = wq * (fv * cp + iv * gv) + (vfh - wq) * cp + (vih - wq) * gv; \
      float h = ov * ftanhf(c);                                        \
      out[rowg * 1024 + jg] = h;                                       \
      out[8388608 + rowg * 1024 + jg] = c;                             \
    }                                                                  \
    __syncthreads();                                                   \
  } while (0)
  EPIPASS(0); EPIPASS(1); EPIPASS(2); EPIPASS(3);
#undef EPIPASS
}

// -------------------------------------------------------------- launcher ---
extern "C" void kernel_launch(void* const* d_in, const int* in_sizes, int n_in,
                              void* d_out, int out_size, void* d_ws, size_t ws_size,
                              hipStream_t stream) {
  (void)in_sizes; (void)n_in; (void)out_size; (void)ws_size;
  const float* inp   = (const float*)d_in[0];
  const float* hprev = (const float*)d_in[1];
  const float* cprev = (const float*)d_in[2];
  const float* wl    = (const float*)d_in[3];
  const float* wlev  = (const float*)d_in[4];
  float* out = (float*)d_out;
  char* ws = (char*)d_ws;

  u16* Ahi  = (u16*)(ws);
  u16* Alo  = (u16*)(ws + 33554432);
  u16* Whi  = (u16*)(ws + 67108864);
  u16* Wlo  = (u16*)(ws + 84410368);
  float* part = (float*)(ws + 84934656);
  float* ih   = (float*)(ws + 118489088);
  float* fh   = (float*)(ws + 120586240);

  k_convert<<<dim3(2048), dim3(256), 0, stream>>>(inp, hprev, wl, wlev, Ahi, Alo, Whi, Wlo);
  k_gemm_level<<<dim3(64, 8), dim3(256), 0, stream>>>(Ahi, Alo, Whi, Wlo, part);
  k_softmax<<<dim3(2048), dim3(256), 0, stream>>>(part, ih, fh);
  k_gemm_main<<<dim3(512), dim3(512), 0, stream>>>(Ahi, Whi, cprev, ih, fh, out);
}